// Round 4
// baseline (77.263 us; speedup 1.0000x reference)
//
#include <hip/hip_runtime.h>

// out[b,s,:] = W[:, text[b,s]] + bias + pe[s,:]
// text: int32 [B,S]; W: f32 [D, VOCAB]; bias: f32 [D]; pe: f32 [MAX_LEN, D]
//
// Round 4: counting-sort (rounds 2/3) + barrier-free 1-wave gather tiles.
// Each wave owns a private 16-token x 64-d tile: 16 lanes over sorted tokens
// (line-sharing ~4x) x 4 d-groups, 16 independent strided loads per lane kept
// in registers -> max outstanding misses per wave. No __syncthreads; 32
// waves/CU; latency-bound model: time ~ requests x latency / in-flight.

#define VOCAB  32000
#define DMODEL 1024
#define S_LEN  2048
#define B_N    4
#define NTOK   (B_N * S_LEN)   // 8192
#define NXCD   8

#define T_CHUNK 16                       // sorted tokens per wave-tile
#define WAVE_D  64                       // d-rows per wave-tile
#define WPB     2                        // independent waves per block
#define D_PER_BLOCK (WAVE_D * WPB)       // 128
#define NTCH    (NTOK / T_CHUNK)         // 512
#define NDCH    (DMODEL / D_PER_BLOCK)   // 8
#define NBLK    (NTCH * NDCH)            // 4096
#define ROW_STRIDE (WAVE_D + 5)          // 69: 2-way LDS aliasing only (free)

// ---- pass 1: histogram of tokens ----
__global__ __launch_bounds__(256) void hist_k(const int* __restrict__ text,
                                              int* __restrict__ hist) {
    int i = blockIdx.x * 256 + threadIdx.x;
    if (i < NTOK) atomicAdd(&hist[text[i]], 1);
}

// ---- pass 2: exclusive scan over 32000 bins (single block) ----
__global__ __launch_bounds__(1024) void scan_k(int* __restrict__ hist) {
    __shared__ int part[1024];
    const int t = threadIdx.x;
    const int base = t * 32;
    int local[32];
    int s = 0;
    #pragma unroll
    for (int j = 0; j < 32; ++j) {
        int idx = base + j;
        int v = (idx < VOCAB) ? hist[idx] : 0;
        local[j] = s;
        s += v;
    }
    part[t] = s;
    __syncthreads();
    for (int off = 1; off < 1024; off <<= 1) {
        int v = (t >= off) ? part[t - off] : 0;
        __syncthreads();
        part[t] += v;
        __syncthreads();
    }
    const int excl = (t == 0) ? 0 : part[t - 1];
    #pragma unroll
    for (int j = 0; j < 32; ++j) {
        int idx = base + j;
        if (idx < VOCAB) hist[idx] = excl + local[j];
    }
}

// ---- pass 3: scatter (token, bs) into sorted order ----
__global__ __launch_bounds__(256) void scatter_k(const int* __restrict__ text,
                                                 int* __restrict__ offs,
                                                 int2* __restrict__ sorted) {
    int i = blockIdx.x * 256 + threadIdx.x;
    if (i < NTOK) {
        int tok = text[i];
        int slot = atomicAdd(&offs[tok], 1);
        sorted[slot] = make_int2(tok, i);
    }
}

// ---- pass 4: barrier-free wave-tile gather ----
__global__ __launch_bounds__(128, 8) void gather_k(const int2* __restrict__ sorted,
                                                   const float* __restrict__ W,
                                                   const float* __restrict__ bias,
                                                   const float* __restrict__ pe,
                                                   float* __restrict__ out) {
    __shared__ float lds[WPB][T_CHUNK][ROW_STRIDE];   // 8.8 KB

    // XCD swizzle: blk%8 -> XCD; each XCD gets a contiguous sorted-token range.
    const int phys = blockIdx.x;
    const int gw = ((phys & (NXCD - 1)) << 9) | (phys >> 3);  // 4096 = 8*512
    const int tchunk = gw >> 3;          // /NDCH -> 0..511
    const int dchunk = gw & (NDCH - 1);

    const int tid  = threadIdx.x;
    const int w    = tid >> 6;           // wave id in block (independent tiles)
    const int lane = tid & 63;
    const int tbase = tchunk * T_CHUNK;
    const int dbase = dchunk * D_PER_BLOCK + w * WAVE_D;

    // ---- phase 1: 16 independent strided W loads, lanes over sorted tokens ----
    {
        const int tl = lane & (T_CHUNK - 1);   // token lane 0..15
        const int dg = lane >> 4;              // d-group 0..3
        const int tok = sorted[tbase + tl].x;
        const float* wp = W + (size_t)(dbase + dg * 16) * VOCAB + tok;
        float v[16];
        #pragma unroll
        for (int i = 0; i < 16; ++i) v[i] = wp[(size_t)i * VOCAB];
        #pragma unroll
        for (int i = 0; i < 16; ++i) lds[w][tl][dg * 16 + i] = v[i];
    }
    // same-wave LDS write->read: compiler orders via lgkmcnt; no barrier needed

    // ---- phase 2: add bias + pe, lanes over d, write out ----
    {
        const int d = dbase + lane;
        const float bv = bias[d];
        #pragma unroll 8
        for (int t = 0; t < T_CHUNK; ++t) {
            const int bs = sorted[tbase + t].y;
            const int s  = bs & (S_LEN - 1);
            const float pv = pe[(size_t)s * DMODEL + d];
            out[(size_t)bs * DMODEL + d] = lds[w][t][lane] + bv + pv;
        }
    }
}

// ---- fallback (ws too small): direct gather ----
__global__ __launch_bounds__(256) void embed_pe_direct(const int* __restrict__ text,
                                                       const float* __restrict__ W,
                                                       const float* __restrict__ bias,
                                                       const float* __restrict__ pe,
                                                       float* __restrict__ out) {
    const int bs = blockIdx.x;
    const int s  = bs & (S_LEN - 1);
    const int tok = text[bs];
    const int d = threadIdx.x << 2;
    const float4 b4 = *reinterpret_cast<const float4*>(bias + d);
    const float4 p4 = *reinterpret_cast<const float4*>(pe + (size_t)s * DMODEL + d);
    const float* wcol = W + (size_t)d * VOCAB + tok;
    float4 o;
    o.x = wcol[0]                 + b4.x + p4.x;
    o.y = wcol[(size_t)VOCAB]     + b4.y + p4.y;
    o.z = wcol[(size_t)2 * VOCAB] + b4.z + p4.z;
    o.w = wcol[(size_t)3 * VOCAB] + b4.w + p4.w;
    *reinterpret_cast<float4*>(out + (size_t)bs * DMODEL + d) = o;
}

extern "C" void kernel_launch(void* const* d_in, const int* in_sizes, int n_in,
                              void* d_out, int out_size, void* d_ws, size_t ws_size,
                              hipStream_t stream) {
    const int*   text = (const int*)d_in[0];
    const float* W    = (const float*)d_in[1];
    const float* bias = (const float*)d_in[2];
    const float* pe   = (const float*)d_in[3];
    float*       out  = (float*)d_out;

    const size_t hist_bytes   = (size_t)VOCAB * sizeof(int);
    const size_t sorted_bytes = (size_t)NTOK * sizeof(int2);
    if (ws_size < hist_bytes + sorted_bytes) {
        embed_pe_direct<<<NTOK, 256, 0, stream>>>(text, W, bias, pe, out);
        return;
    }

    int*  hist   = (int*)d_ws;
    int2* sorted = (int2*)((char*)d_ws + hist_bytes);

    hipMemsetAsync(hist, 0, hist_bytes, stream);
    hist_k   <<<(NTOK + 255) / 256, 256, 0, stream>>>(text, hist);
    scan_k   <<<1, 1024, 0, stream>>>(hist);
    scatter_k<<<(NTOK + 255) / 256, 256, 0, stream>>>(text, hist, sorted);
    gather_k <<<NBLK, 128, 0, stream>>>(sorted, W, bias, pe, out);
}

// Round 5
// 42.716 us; speedup vs baseline: 1.8088x; 1.8088x over previous
//
#include <hip/hip_runtime.h>

// out[b,s,:] = W[:, text[b,s]] + bias + pe[s,:]
// text: int32 [B,S]; W: f32 [D, VOCAB]; bias: f32 [D]; pe: f32 [MAX_LEN, D]
//
// Round 5: kill the scattered-load wall (~0.2 divergent dwords/cyc/CU measured
// across rounds 2-4) by never issuing scattered global accesses. Sweep ALL of
// W coalesced in (64 d x 128 vocab) tiles staged in LDS; tokens are pre-binned
// by vocab-tile; each token's out-row-piece is read from LDS columns
// (stride-129 = conflict-free) and written coalesced with bias+pe fused.

#define VOCAB  32000
#define DMODEL 1024
#define S_LEN  2048
#define B_N    4
#define NTOK   (B_N * S_LEN)     // 8192
#define VT     128               // vocab entries per tile
#define DT     64                // d rows per tile
#define NBIN   (VOCAB / VT)      // 250
#define NDT    (DMODEL / DT)     // 16
#define NBLK   (NBIN * NDT)      // 4000
#define LSTRIDE (VT + 1)         // 129: column reads conflict-free

// ---- pass 1: bin tokens by vocab-tile (single block, does hist+scan+scatter) ----
__global__ __launch_bounds__(1024) void bin_k(const int* __restrict__ text,
                                              int2* __restrict__ sorted,
                                              int* __restrict__ tile_off) {
    __shared__ int cnt[256];
    __shared__ int scn[256];
    const int t = threadIdx.x;
    if (t < 256) cnt[t] = 0;
    __syncthreads();

    int toks[8];
    #pragma unroll
    for (int j = 0; j < 8; ++j) {
        toks[j] = text[t * 8 + j];
        atomicAdd(&cnt[toks[j] >> 7], 1);
    }
    __syncthreads();

    // inclusive Hillis-Steele scan over 256 bins (250 used)
    if (t < 256) scn[t] = cnt[t];
    __syncthreads();
    for (int off = 1; off < 256; off <<= 1) {
        int x = 0;
        if (t < 256 && t >= off) x = scn[t - off];
        __syncthreads();
        if (t < 256) scn[t] += x;
        __syncthreads();
    }
    if (t < 256) {
        const int start = scn[t] - cnt[t];   // exclusive
        tile_off[t] = start;                 // tile_off[250] = 8192 (empty bins)
        cnt[t] = start;                      // reuse as running slot counter
    }
    __syncthreads();

    #pragma unroll
    for (int j = 0; j < 8; ++j) {
        const int tok = toks[j];
        const int slot = atomicAdd(&cnt[tok >> 7], 1);
        sorted[slot] = make_int2(tok, t * 8 + j);
    }
}

// ---- pass 2: coalesced W sweep, LDS-staged scatter-free gather ----
__global__ __launch_bounds__(256) void gather_k(const int2* __restrict__ sorted,
                                                const int* __restrict__ tile_off,
                                                const float* __restrict__ W,
                                                const float* __restrict__ bias,
                                                const float* __restrict__ pe,
                                                float* __restrict__ out) {
    __shared__ float lds[DT * LSTRIDE];      // 33 KB

    const int bid = blockIdx.x;
    const int vt = bid >> 4;                 // 0..249
    const int dt = bid & (NDT - 1);          // 0..15
    const int v0 = vt * VT;
    const int d0 = dt * DT;
    const int t  = threadIdx.x;

    // stage W[d0:d0+64][v0:v0+128] into LDS, fully coalesced float4 reads
    {
        const int c4 = t & 31;               // float4 column 0..31
        const int r0 = t >> 5;               // 0..7
        #pragma unroll
        for (int i = 0; i < 8; ++i) {
            const int row = r0 + i * 8;
            const float4 w4 = *reinterpret_cast<const float4*>(
                W + (size_t)(d0 + row) * VOCAB + v0 + c4 * 4);
            float* lp = lds + row * LSTRIDE + c4 * 4;
            lp[0] = w4.x; lp[1] = w4.y; lp[2] = w4.z; lp[3] = w4.w;
        }
    }
    __syncthreads();

    const int a0 = tile_off[vt];
    const int a1 = tile_off[vt + 1];
    const int lane = t & 63;
    const int wv   = t >> 6;                 // wave id: 4 tokens in parallel
    const float bv = bias[d0 + lane];

    for (int i = a0 + wv; i < a1; i += 4) {
        const int2 p = sorted[i];            // wave-uniform
        const int tokl = p.x - v0;
        const int bs   = p.y;
        const int s    = bs & (S_LEN - 1);
        const float wval = lds[lane * LSTRIDE + tokl];   // conflict-free column
        const float pv = pe[(size_t)s * DMODEL + d0 + lane];
        out[(size_t)bs * DMODEL + d0 + lane] = wval + bv + pv;
    }
}

// ---- fallback (ws too small): direct gather ----
__global__ __launch_bounds__(256) void embed_pe_direct(const int* __restrict__ text,
                                                       const float* __restrict__ W,
                                                       const float* __restrict__ bias,
                                                       const float* __restrict__ pe,
                                                       float* __restrict__ out) {
    const int bs = blockIdx.x;
    const int s  = bs & (S_LEN - 1);
    const int tok = text[bs];
    const int d = threadIdx.x << 2;
    const float4 b4 = *reinterpret_cast<const float4*>(bias + d);
    const float4 p4 = *reinterpret_cast<const float4*>(pe + (size_t)s * DMODEL + d);
    const float* wcol = W + (size_t)d * VOCAB + tok;
    float4 o;
    o.x = wcol[0]                 + b4.x + p4.x;
    o.y = wcol[(size_t)VOCAB]     + b4.y + p4.y;
    o.z = wcol[(size_t)2 * VOCAB] + b4.z + p4.z;
    o.w = wcol[(size_t)3 * VOCAB] + b4.w + p4.w;
    *reinterpret_cast<float4*>(out + (size_t)bs * DMODEL + d) = o;
}

extern "C" void kernel_launch(void* const* d_in, const int* in_sizes, int n_in,
                              void* d_out, int out_size, void* d_ws, size_t ws_size,
                              hipStream_t stream) {
    const int*   text = (const int*)d_in[0];
    const float* W    = (const float*)d_in[1];
    const float* bias = (const float*)d_in[2];
    const float* pe   = (const float*)d_in[3];
    float*       out  = (float*)d_out;

    const size_t sorted_bytes = (size_t)NTOK * sizeof(int2);   // 64 KB
    const size_t off_bytes    = 257 * sizeof(int);
    if (ws_size < sorted_bytes + off_bytes) {
        embed_pe_direct<<<NTOK, 256, 0, stream>>>(text, W, bias, pe, out);
        return;
    }

    int2* sorted   = (int2*)d_ws;
    int*  tile_off = (int*)((char*)d_ws + sorted_bytes);

    bin_k   <<<1, 1024, 0, stream>>>(text, sorted, tile_off);
    gather_k<<<NBLK, 256, 0, stream>>>(sorted, tile_off, W, bias, pe, out);
}